// Round 1
// baseline (91.066 us; speedup 1.0000x reference)
//
#include <hip/hip_runtime.h>

// ConditionalSigmoid: hierarchical conditional-probability sigmoid loss.
// B=4096 rows, N=8192 nodes, levels [8,128,2048,6008] -> level starts 0,8,136,2184.
// Outputs (f32): d_out[0] = loss scalar, d_out[1..] = pred_clone [B,N].

#define N_NODES 8192
#define L1S 8      // level-1 start
#define L2S 136    // level-2 start
#define L3S 2184   // level-3 start (all parents are < L3S)
#define EPSF 1e-7f

__device__ __forceinline__ float sigmoidf(float x) {
    return 1.0f / (1.0f + __expf(-x));
}

// One block per batch row. bsum != nullptr: write per-block partial loss there
// (deterministic two-pass). bsum == nullptr: atomicAdd scaled partial to out[0].
__global__ __launch_bounds__(256) void cs_main(
    const float* __restrict__ pred,
    const float* __restrict__ target,
    const int* __restrict__ parent,
    float* __restrict__ out,      // out+1 = pred_clone base
    float* __restrict__ bsum,
    float inv_b)
{
    __shared__ float pc[L3S];   // cumulative ancestor-chain prob, levels 0..2
    __shared__ float tg[L3S];   // staged target row (mask gather source)
    __shared__ float red[4];

    const int tid = threadIdx.x;
    const int b = blockIdx.x;
    const float* __restrict__ prow = pred + (size_t)b * N_NODES;
    const float* __restrict__ trow = target + (size_t)b * N_NODES;
    float* __restrict__ orow = out + 1 + (size_t)b * N_NODES;

    float lsum = 0.0f;

    // ---- Phase 1: nodes [0, L3S): stage p & target in LDS, loss terms ----
    for (int c4 = tid; c4 < L3S / 4; c4 += 256) {
        const int c0 = c4 * 4;
        const float4 x4 = ((const float4*)prow)[c4];
        const float4 t4 = ((const float4*)trow)[c4];
        const int4  q4 = ((const int4*)parent)[c4];
        const float xs[4] = {x4.x, x4.y, x4.z, x4.w};
        const float ts[4] = {t4.x, t4.y, t4.z, t4.w};
        const int   qs[4] = {q4.x, q4.y, q4.z, q4.w};
#pragma unroll
        for (int j = 0; j < 4; ++j) {
            const float p = sigmoidf(xs[j]);
            pc[c0 + j] = p;
            tg[c0 + j] = ts[j];
            // mask: roots -> 1, else target[b, parent[c]] (parent < 136 here or < L3S)
            const float mask = (qs[j] < 0) ? 1.0f : trow[qs[j]];
            const float pcl = fminf(fmaxf(p, EPSF), 1.0f - EPSF);
            lsum -= __logf(pcl) * ts[j] + (1.0f - ts[j]) * mask * __logf(1.0f - pcl);
        }
    }
    __syncthreads();
    // fold level-1 chain: pc[c] *= pc[parent] (parent is level-0, final)
    for (int c = L1S + tid; c < L2S; c += 256) pc[c] *= pc[parent[c]];
    __syncthreads();
    // fold level-2 chain (parent is level-1, final after barrier)
    for (int c = L2S + tid; c < L3S; c += 256) pc[c] *= pc[parent[c]];
    __syncthreads();
    // write pred_clone for levels 0..2 (stride-1 coalesced)
    for (int c = tid; c < L3S; c += 256) orow[c] = pc[c];

    // ---- Phase 2: level-3 nodes [L3S, N): one LDS gather each ----
    for (int c4 = L3S / 4 + tid; c4 < N_NODES / 4; c4 += 256) {
        const int c0 = c4 * 4;
        const float4 x4 = ((const float4*)prow)[c4];
        const float4 t4 = ((const float4*)trow)[c4];
        const int4  q4 = ((const int4*)parent)[c4];
        const float xs[4] = {x4.x, x4.y, x4.z, x4.w};
        const float ts[4] = {t4.x, t4.y, t4.z, t4.w};
        const int   qs[4] = {q4.x, q4.y, q4.z, q4.w};
#pragma unroll
        for (int j = 0; j < 4; ++j) {
            const float p = sigmoidf(xs[j]);
            const int pa = qs[j];                 // in [136, 2184)
            const float mask = tg[pa];
            const float pcl = fminf(fmaxf(p, EPSF), 1.0f - EPSF);
            lsum -= __logf(pcl) * ts[j] + (1.0f - ts[j]) * mask * __logf(1.0f - pcl);
            orow[c0 + j] = p * pc[pa];            // conditional prob propagation
        }
    }

    // ---- block reduction of loss partial ----
#pragma unroll
    for (int off = 32; off > 0; off >>= 1) lsum += __shfl_down(lsum, off);
    if ((tid & 63) == 0) red[tid >> 6] = lsum;
    __syncthreads();
    if (tid == 0) {
        const float s = (red[0] + red[1]) + (red[2] + red[3]);
        if (bsum) bsum[blockIdx.x] = s;
        else atomicAdd(out, s * inv_b);
    }
}

// Deterministic final reduction of per-block partials.
__global__ __launch_bounds__(256) void cs_finish(
    const float* __restrict__ bsum, float* __restrict__ out,
    int nblocks, float inv_b)
{
    __shared__ float red[4];
    const int tid = threadIdx.x;
    float s = 0.0f;
    for (int i = tid; i < nblocks; i += 256) s += bsum[i];
#pragma unroll
    for (int off = 32; off > 0; off >>= 1) s += __shfl_down(s, off);
    if ((tid & 63) == 0) red[tid >> 6] = s;
    __syncthreads();
    if (tid == 0) out[0] = ((red[0] + red[1]) + (red[2] + red[3])) * inv_b;
}

extern "C" void kernel_launch(void* const* d_in, const int* in_sizes, int n_in,
                              void* d_out, int out_size, void* d_ws, size_t ws_size,
                              hipStream_t stream) {
    const float* pred   = (const float*)d_in[0];
    const float* target = (const float*)d_in[1];
    const int*   parent = (const int*)d_in[2];
    // d_in[3] = level_of (implied by hardcoded level starts), d_in[4] = mode (0 = EVAL)

    float* out = (float*)d_out;
    const int batch = in_sizes[0] / N_NODES;   // 4096
    const float inv_b = 1.0f / (float)batch;

    if (ws_size >= (size_t)batch * sizeof(float)) {
        float* bsum = (float*)d_ws;
        cs_main<<<batch, 256, 0, stream>>>(pred, target, parent, out, bsum, inv_b);
        cs_finish<<<1, 256, 0, stream>>>(bsum, out, batch, inv_b);
    } else {
        hipMemsetAsync(d_out, 0, sizeof(float), stream);
        cs_main<<<batch, 256, 0, stream>>>(pred, target, parent, out, nullptr, inv_b);
    }
}